// Round 7
// baseline (523.649 us; speedup 1.0000x reference)
//
#include <hip/hip_runtime.h>
#include <cstdint>
#include <cstddef>

#define NEG_SLOPE 0.2f
#define BIN_SHIFT 9      // 512 nodes per bucket
#define BCAP 16384       // fixed tmpE capacity per bucket (expected ~8700, ~80 sigma margin)
#define LOG2E 1.4426950408889634f

typedef short bf16x8 __attribute__((ext_vector_type(8)));
typedef float f32x4 __attribute__((ext_vector_type(4)));

#if __has_builtin(__builtin_amdgcn_exp2f)
#define EXP2(x) __builtin_amdgcn_exp2f(x)
#else
#define EXP2(x) exp2f(x)
#endif

// fp32 -> bf16 RTNE
static __device__ __forceinline__ unsigned short bf16r(float f) {
    unsigned u = __float_as_uint(f);
    return (unsigned short)((u + 0x7fffu + ((u >> 16) & 1u)) >> 16);
}
static __device__ __forceinline__ float bfu_lo(unsigned u) { return __uint_as_float(u << 16); }
static __device__ __forceinline__ float bfu_hi(unsigned u) { return __uint_as_float(u & 0xffff0000u); }

// ---------------- W prep: bf16 hi/lo split into MFMA-fragment-contiguous layout + bcnt zero ----------------
// WB[ks][f][lane][8]: element (col=f*16+l15, k=ks*32+lh*8+j) at ((ks*8+f)*64 + lh*16+l15)*8 + j.
__global__ __launch_bounds__(256) void wprep_k(const float* __restrict__ W1, const float* __restrict__ W2,
                                               unsigned short* __restrict__ Wh1, unsigned short* __restrict__ Wl1,
                                               unsigned short* __restrict__ Wh2, unsigned short* __restrict__ Wl2,
                                               int* __restrict__ bcnt) {
    if (blockIdx.x == 0) bcnt[threadIdx.x] = 0;
    int t = blockIdx.x * 256 + threadIdx.x;       // grid 128 -> 32768 threads
    const float* W;
    unsigned short *Wh, *Wl;
    int idx;
    if (t < 16384) { W = W1; Wh = Wh1; Wl = Wl1; idx = t; }
    else           { W = W2; Wh = Wh2; Wl = Wl2; idx = t - 16384; }
    int c = idx >> 7;     // output col 0..127
    int k = idx & 127;    // input k 0..127
    float w = W[(size_t)k * 128 + c];
    unsigned short h = bf16r(w);
    float lo = w - __uint_as_float((unsigned)h << 16);
    int dst = (k >> 5) * 4096 + (c >> 4) * 512 + (((k >> 3) & 3) * 16 + (c & 15)) * 8 + (k & 7);
    Wh[dst] = h;
    Wl[dst] = bf16r(lo);
}

// ---------------- Phase A: bin edges (incl. self-loops) into fixed-capacity dst buckets ----------------
// tmpE entry packed: (src << 9) | (dst & 511)
__global__ __launch_bounds__(256) void bin_k(const int* __restrict__ srcI, const int* __restrict__ dstI,
                                             int E, int N, int K, int* __restrict__ bcnt,
                                             int* __restrict__ tmpE) {
    __shared__ int hist[256];
    __shared__ int lbase[256];
    const int t = threadIdx.x;
    const int M = E + N;
    const int chunk0 = blockIdx.x * 4096;
    hist[t] = 0;
    __syncthreads();

    int s[16], d[16], b[16];
#pragma unroll
    for (int j = 0; j < 16; ++j) {
        int i = chunk0 + t + j * 256;
        b[j] = -1;
        if (i < M) {
            int ss, dd;
            if (i < E) { ss = srcI[i]; dd = dstI[i]; }
            else       { ss = i - E;  dd = ss; }
            if ((unsigned)dd < (unsigned)N && (unsigned)ss < (unsigned)N) {
                s[j] = ss; d[j] = dd; b[j] = dd >> BIN_SHIFT;
                atomicAdd(&hist[b[j]], 1);
            }
        }
    }
    __syncthreads();
    if (t < K) {
        int c = hist[t];
        lbase[t] = (c > 0) ? atomicAdd(&bcnt[t], c) : 0;
    }
    hist[t] = 0;   // safe: each index touched only by its own thread before the next barrier
    __syncthreads();
#pragma unroll
    for (int j = 0; j < 16; ++j) {
        if (b[j] >= 0) {
            int r = atomicAdd(&hist[b[j]], 1);
            int pos = lbase[b[j]] + r;
            if (pos < BCAP) tmpE[(size_t)b[j] * BCAP + pos] = (s[j] << 9) | (d[j] & 511);
        }
    }
}

// ---------------- Phase B: per-bucket local CSR build + scatter; colOff = src*64 (head-plane row byte offset) ----------------
__global__ __launch_bounds__(256) void scatter_csr_k(const int* __restrict__ tmpE,
                                                     const int* __restrict__ bcnt,
                                                     int* __restrict__ rowptr,
                                                     int* __restrict__ colOff,
                                                     int N, int K) {
    __shared__ int pre[256];
    __shared__ int cur[512];
    __shared__ int ss[256];
    const int t = threadIdx.x;
    const int b = blockIdx.x;

    int bc = (t < K) ? min(bcnt[t], BCAP) : 0;
    pre[t] = bc;
    __syncthreads();
    for (int off = 1; off < 256; off <<= 1) {
        int v = (t >= off) ? pre[t - off] : 0;
        __syncthreads();
        pre[t] += v;
        __syncthreads();
    }
    const int base_b = (b == 0) ? 0 : pre[b - 1];
    const int cnt_b  = pre[b] - base_b;
    if (b == K - 1 && t == 0) rowptr[N] = pre[K - 1];

    const int nlo = b << BIN_SHIFT;
    const int nhi = min(nlo + (1 << BIN_SHIFT), N);
    const int nn  = nhi - nlo;
    const int* te = tmpE + (size_t)b * BCAP;

    cur[t] = 0;
    cur[t + 256] = 0;
    __syncthreads();
    for (int i = t; i < cnt_b; i += 256) atomicAdd(&cur[te[i] & 511], 1);
    __syncthreads();

    int v0 = cur[2 * t], v1 = cur[2 * t + 1];
    ss[t] = v0 + v1;
    __syncthreads();
    for (int off = 1; off < 256; off <<= 1) {
        int v = (t >= off) ? ss[t - off] : 0;
        __syncthreads();
        ss[t] += v;
        __syncthreads();
    }
    int e0 = (t == 0) ? 0 : ss[t - 1];
    int e1 = e0 + v0;
    if (2 * t < nn)     rowptr[nlo + 2 * t]     = base_b + e0;
    if (2 * t + 1 < nn) rowptr[nlo + 2 * t + 1] = base_b + e1;
    cur[2 * t] = e0;
    cur[2 * t + 1] = e1;
    __syncthreads();

    for (int i = t; i < cnt_b; i += 256) {
        int v = te[i];
        int r = atomicAdd(&cur[v & 511], 1);
        colOff[base_b + r] = ((unsigned)v >> 9) << 6;   // byte offset of src's 64B plane row
    }
}

// ---------------- h = X @ W via split-bf16 MFMA; head-plane bf16 Hout + log2e-scaled fp32 alphas ----------------
// X@W ~= Xh@Wh + Xl@Wh + Xh@Wl (dropped Xl@Wl ~2^-18) -> fp32-grade accuracy.
// Hout is 4 head-planes of N x 64B: plane h holds cols [h*32, h*32+32) as bf16.
__global__ __launch_bounds__(256) void gemm_mfma_k(const float* __restrict__ X,
                                                   const unsigned short* __restrict__ Wh,
                                                   const unsigned short* __restrict__ Wl,
                                                   const float* __restrict__ a_s,
                                                   const float* __restrict__ a_d,
                                                   char* __restrict__ Hout,
                                                   float* __restrict__ asrc,
                                                   float* __restrict__ adst,
                                                   int N, int planeB) {
    __shared__ __align__(16) unsigned short hstage[4][32][132];  // +4 pad: conflict-light
    const int tid = threadIdx.x;
    const int wid = tid >> 6;
    const int l   = tid & 63;
    const int l15 = l & 15;
    const int lh  = l >> 4;
    const int waveRow = blockIdx.x * 128 + wid * 32;
    if (waveRow >= N) return;

    f32x4 acc[2][8];
#pragma unroll
    for (int m = 0; m < 2; ++m)
#pragma unroll
        for (int f = 0; f < 8; ++f)
#pragma unroll
            for (int c = 0; c < 4; ++c) acc[m][f][c] = 0.f;

    const int r0 = waveRow + l15;
    const int r1 = waveRow + 16 + l15;
    const size_t xoff0 = (size_t)min(r0, N - 1) * 128;   // clamp: junk rows never stored
    const size_t xoff1 = (size_t)min(r1, N - 1) * 128;
    const int kb = lh * 8;

#pragma unroll
    for (int ks = 0; ks < 4; ++ks) {
        bf16x8 ah[2], al[2];
#pragma unroll
        for (int m = 0; m < 2; ++m) {
            const float* xp = X + (m ? xoff1 : xoff0) + ks * 32 + kb;
            float4 v0 = *(const float4*)xp;
            float4 v1 = *(const float4*)(xp + 4);
            float xs[8] = {v0.x, v0.y, v0.z, v0.w, v1.x, v1.y, v1.z, v1.w};
#pragma unroll
            for (int j = 0; j < 8; ++j) {
                unsigned short h = bf16r(xs[j]);
                float hf = __uint_as_float((unsigned)h << 16);
                ah[m][j] = (short)h;
                al[m][j] = (short)bf16r(xs[j] - hf);
            }
        }
        const unsigned short* wbh = Wh + ks * 4096 + l * 8;
        const unsigned short* wbl = Wl + ks * 4096 + l * 8;
#pragma unroll
        for (int f = 0; f < 8; ++f) {
            bf16x8 wh = *(const bf16x8*)(wbh + f * 512);
            bf16x8 wl = *(const bf16x8*)(wbl + f * 512);
#pragma unroll
            for (int m = 0; m < 2; ++m) {
                acc[m][f] = __builtin_amdgcn_mfma_f32_16x16x32_bf16(ah[m], wh, acc[m][f], 0, 0, 0);
                acc[m][f] = __builtin_amdgcn_mfma_f32_16x16x32_bf16(al[m], wh, acc[m][f], 0, 0, 0);
                acc[m][f] = __builtin_amdgcn_mfma_f32_16x16x32_bf16(ah[m], wl, acc[m][f], 0, 0, 0);
            }
        }
    }

    float asf[8], adf[8];
#pragma unroll
    for (int f = 0; f < 8; ++f) {
        asf[f] = a_s[f * 16 + l15];
        adf[f] = a_d[f * 16 + l15];
    }
    const int q = l15;
#pragma unroll
    for (int m = 0; m < 2; ++m) {
#pragma unroll
        for (int r = 0; r < 4; ++r) {
            float ps[4] = {0.f, 0.f, 0.f, 0.f};
            float pd[4] = {0.f, 0.f, 0.f, 0.f};
#pragma unroll
            for (int f = 0; f < 8; ++f) {
                float v = acc[m][f][r];
                ps[f >> 1] = fmaf(v, asf[f], ps[f >> 1]);
                pd[f >> 1] = fmaf(v, adf[f], pd[f >> 1]);
                hstage[wid][m * 16 + lh * 4 + r][f * 16 + l15] = bf16r(v);
            }
#pragma unroll
            for (int mask = 1; mask < 16; mask <<= 1) {
#pragma unroll
                for (int h = 0; h < 4; ++h) {
                    ps[h] += __shfl_xor(ps[h], mask);
                    pd[h] += __shfl_xor(pd[h], mask);
                }
            }
            int row = waveRow + m * 16 + lh * 4 + r;
            if (q < 8 && row < N) {
                float v0 = (q & 1) ? ps[1] : ps[0];
                float v1 = (q & 1) ? ps[3] : ps[2];
                float vs = (q & 2) ? v1 : v0;
                float w0 = (q & 1) ? pd[1] : pd[0];
                float w1 = (q & 1) ? pd[3] : pd[2];
                float vd = (q & 2) ? w1 : w0;
                // pre-scale by log2(e): aggregate uses native exp2 (lrelu is pos-homogeneous)
                if (q < 4) asrc[row * 4 + q] = vs * LOG2E;
                else       adst[row * 4 + (q - 4)] = vd * LOG2E;
            }
        }
    }

    // bf16 store into head planes: lane l15 covers cols l15*8..+8 -> head = l15>>2, chunk (l15&3)*16B
#pragma unroll
    for (int it = 0; it < 8; ++it) {
        int row = it * 4 + lh;
        const unsigned short* hp = &hstage[wid][row][l15 * 8];
        uint2 aa = *(const uint2*)hp;
        uint2 bb = *(const uint2*)(hp + 4);
        int grow = waveRow + row;
        if (grow < N) {
            uint4 o;
            o.x = aa.x; o.y = aa.y; o.z = bb.x; o.w = bb.y;
            char* dst = Hout + (size_t)(l15 >> 2) * planeB + (size_t)grow * 64 + (l15 & 3) * 16;
            *(uint4*)dst = o;
        }
    }
}

// ---------------- aggregation: head-plane blocks XCD-pinned; wave = 1 node x 1 head, 4 edge-slots ----------------
// bid = grp*4 + head -> under blockIdx%8 XCD round-robin, head h runs on XCDs {h, h+4} only,
// so each XCD's L2 caches ONE 6.4MB head-plane instead of the full 25.6MB Hbuf.
// w = exp2(lrelu(asrc'+adst')) with alphas pre-scaled by log2e. Tail lanes: w=0 exact.
__global__ __launch_bounds__(256) void aggregate_k(const char* __restrict__ Hb,
                                                   const float* __restrict__ asrc,
                                                   const float* __restrict__ adst,
                                                   const int* __restrict__ rowptr,
                                                   const int* __restrict__ colOff,
                                                   const float* __restrict__ bias,
                                                   float* __restrict__ out, int N, int planeB) {
    const int head = blockIdx.x & 3;
    const int grp  = blockIdx.x >> 2;
    const int wid  = threadIdx.x >> 6;
    const int lane = threadIdx.x & 63;
    const int g    = lane >> 4;       // edge slot 0..3
    const int li   = lane & 15;       // channel dword within head (2 ch)
    const char* plane = Hb + (size_t)head * planeB;
    const char* As = (const char*)asrc;
    const int aoff = head * 4;
    const int hoff = li * 4;
    const float2 bv = *(const float2*)&bias[head * 32 + li * 2];

    const int n0 = grp * 16 + wid * 4;
#pragma unroll 1
    for (int i = 0; i < 4; ++i) {
        int n = n0 + i;
        if (n >= N) break;
        int b = __builtin_amdgcn_readfirstlane(rowptr[n]);
        int e = __builtin_amdgcn_readfirstlane(rowptr[n + 1]);
        float adh = adst[n * 4 + head];
        float acc0 = 0.f, acc1 = 0.f, sw = 0.f;
        for (int p = b; p < e; p += 8) {
            int q0 = p + g, q1 = p + 4 + g;
            int off0 = colOff[min(q0, e - 1)];
            int off1 = colOff[min(q1, e - 1)];
            float a0 = *(const float*)(As + (off0 >> 2) + aoff);
            float a1 = *(const float*)(As + (off1 >> 2) + aoff);
            unsigned u0 = *(const unsigned*)(plane + off0 + hoff);
            unsigned u1 = *(const unsigned*)(plane + off1 + hoff);
            float x0 = a0 + adh, x1 = a1 + adh;
            float w0 = (q0 < e) ? EXP2(fmaxf(x0, NEG_SLOPE * x0)) : 0.f;
            float w1 = (q1 < e) ? EXP2(fmaxf(x1, NEG_SLOPE * x1)) : 0.f;
            sw += w0 + w1;
            acc0 = fmaf(w0, bfu_lo(u0), acc0);
            acc1 = fmaf(w0, bfu_hi(u0), acc1);
            acc0 = fmaf(w1, bfu_lo(u1), acc0);
            acc1 = fmaf(w1, bfu_hi(u1), acc1);
        }
        // combine the 4 edge slots (butterfly over lane bits 4 and 5)
        sw   += __shfl_xor(sw, 16);   sw   += __shfl_xor(sw, 32);
        acc0 += __shfl_xor(acc0, 16); acc0 += __shfl_xor(acc0, 32);
        acc1 += __shfl_xor(acc1, 16); acc1 += __shfl_xor(acc1, 32);
        if (g == 0) {
            float inv = 1.f / sw;
            float2 o;
            o.x = fmaxf(acc0 * inv + bv.x, 0.f);
            o.y = fmaxf(acc1 * inv + bv.y, 0.f);
            *(float2*)&out[(size_t)n * 128 + head * 32 + li * 2] = o;
        }
    }
}

// ---------------- launch: 7 dispatches ----------------

extern "C" void kernel_launch(void* const* d_in, const int* in_sizes, int n_in,
                              void* d_out, int out_size, void* d_ws, size_t ws_size,
                              hipStream_t stream) {
    const float* X   = (const float*)d_in[0];
    const int*   EI  = (const int*)d_in[1];
    const float* W1  = (const float*)d_in[2];
    const float* as1 = (const float*)d_in[3];
    const float* ad1 = (const float*)d_in[4];
    const float* b1  = (const float*)d_in[5];
    const float* W2  = (const float*)d_in[6];
    const float* as2 = (const float*)d_in[7];
    const float* ad2 = (const float*)d_in[8];
    const float* b2  = (const float*)d_in[9];

    const int N = in_sizes[0] / 128;
    const int E = in_sizes[1] / 2;
    const int M = E + N;
    const int K = (N + (1 << BIN_SHIFT) - 1) >> BIN_SHIFT;   // <= 256 for N <= 131072
    const int* srcI = EI;
    const int* dstI = EI + E;
    const int planeB = N * 64;                               // bytes per head plane

    char* w = (char*)d_ws;
    auto alloc = [&](size_t bytes) {
        char* p = w;
        w += (bytes + 255) & ~(size_t)255;
        return p;
    };
    char*  Hbuf   = (char*)alloc((size_t)N * 256);           // 4 head planes of N x 64B
    float* asrc   = (float*)alloc((size_t)N * 4 * 4);
    float* adst   = (float*)alloc((size_t)N * 4 * 4);
    int*   rowptr = (int*)alloc((size_t)(N + 1) * 4);
    int*   colOff = (int*)alloc((size_t)M * 4);
    int*   tmpE   = (int*)alloc((size_t)K * BCAP * 4);       // packed (src<<9 | dst&511)
    int*   bcnt   = (int*)alloc(256 * 4);
    unsigned short* Wt1h = (unsigned short*)alloc(128 * 128 * 2);
    unsigned short* Wt1l = (unsigned short*)alloc(128 * 128 * 2);
    unsigned short* Wt2h = (unsigned short*)alloc(128 * 128 * 2);
    unsigned short* Wt2l = (unsigned short*)alloc(128 * 128 * 2);

    const int gemmBlocks = (N + 127) / 128;
    const int aggBlocks  = ((N + 15) / 16) * 4;              // (node-group, head)
    float* out = (float*)d_out;

    // 1: W pre-split (fragment-contiguous layout) + bcnt zeroing
    wprep_k<<<128, 256, 0, stream>>>(W1, W2, Wt1h, Wt1l, Wt2h, Wt2l, bcnt);
    // 2: bin edges into buckets (packed entries)
    bin_k<<<(M + 4095) / 4096, 256, 0, stream>>>(srcI, dstI, E, N, K, bcnt, tmpE);
    // 3: per-bucket CSR build + scatter
    scatter_csr_k<<<K, 256, 0, stream>>>(tmpE, bcnt, rowptr, colOff, N, K);
    // 4: gemm layer 1 (activation staged in d_out, fp32)
    gemm_mfma_k<<<gemmBlocks, 256, 0, stream>>>(X, Wt1h, Wt1l, as1, ad1, Hbuf, asrc, adst, N, planeB);
    // 5: aggregate layer 1
    aggregate_k<<<aggBlocks, 256, 0, stream>>>(Hbuf, asrc, adst, rowptr, colOff, b1, out, N, planeB);
    // 6: gemm layer 2
    gemm_mfma_k<<<gemmBlocks, 256, 0, stream>>>(out, Wt2h, Wt2l, as2, ad2, Hbuf, asrc, adst, N, planeB);
    // 7: aggregate layer 2
    aggregate_k<<<aggBlocks, 256, 0, stream>>>(Hbuf, asrc, adst, rowptr, colOff, b2, out, N, planeB);
}

// Round 8
// 378.267 us; speedup vs baseline: 1.3843x; 1.3843x over previous
//
#include <hip/hip_runtime.h>
#include <cstdint>
#include <cstddef>

#define NEG_SLOPE 0.2f
#define BIN_SHIFT 9      // 512 nodes per bucket
#define BCAP 16384       // fixed tmpE capacity per bucket (expected ~8700, ~80 sigma margin)
#define LOG2E 1.4426950408889634f

typedef short bf16x8 __attribute__((ext_vector_type(8)));
typedef float f32x4 __attribute__((ext_vector_type(4)));

#if __has_builtin(__builtin_amdgcn_exp2f)
#define EXP2(x) __builtin_amdgcn_exp2f(x)
#else
#define EXP2(x) exp2f(x)
#endif

// fp32 -> bf16 RTNE
static __device__ __forceinline__ unsigned short bf16r(float f) {
    unsigned u = __float_as_uint(f);
    return (unsigned short)((u + 0x7fffu + ((u >> 16) & 1u)) >> 16);
}
static __device__ __forceinline__ float bfu_lo(unsigned u) { return __uint_as_float(u << 16); }
static __device__ __forceinline__ float bfu_hi(unsigned u) { return __uint_as_float(u & 0xffff0000u); }

// ---------------- W prep: bf16 hi/lo split into MFMA-fragment-contiguous layout + bcnt zero ----------------
// WB[ks][f][lane][8]: element (col=f*16+l15, k=ks*32+lh*8+j) at ((ks*8+f)*64 + lh*16+l15)*8 + j.
__global__ __launch_bounds__(256) void wprep_k(const float* __restrict__ W1, const float* __restrict__ W2,
                                               unsigned short* __restrict__ Wh1, unsigned short* __restrict__ Wl1,
                                               unsigned short* __restrict__ Wh2, unsigned short* __restrict__ Wl2,
                                               int* __restrict__ bcnt) {
    if (blockIdx.x == 0) bcnt[threadIdx.x] = 0;
    int t = blockIdx.x * 256 + threadIdx.x;       // grid 128 -> 32768 threads
    const float* W;
    unsigned short *Wh, *Wl;
    int idx;
    if (t < 16384) { W = W1; Wh = Wh1; Wl = Wl1; idx = t; }
    else           { W = W2; Wh = Wh2; Wl = Wl2; idx = t - 16384; }
    int c = idx >> 7;     // output col 0..127
    int k = idx & 127;    // input k 0..127
    float w = W[(size_t)k * 128 + c];
    unsigned short h = bf16r(w);
    float lo = w - __uint_as_float((unsigned)h << 16);
    int dst = (k >> 5) * 4096 + (c >> 4) * 512 + (((k >> 3) & 3) * 16 + (c & 15)) * 8 + (k & 7);
    Wh[dst] = h;
    Wl[dst] = bf16r(lo);
}

// ---------------- Phase A: bin edges into fixed-capacity dst buckets; LDS counting sort -> coalesced writes ----------------
// tmpE entry packed: (src << 9) | (dst & 511). Entries are bucket-sorted in LDS first so the
// global write-out walks each bucket's segment sequentially (avg run ~21 entries) instead of
// scattering 64 lanes to ~64 distinct cache lines per store instruction (R5-class pathology).
__global__ __launch_bounds__(256) void bin_k(const int* __restrict__ srcI, const int* __restrict__ dstI,
                                             int E, int N, int K, int* __restrict__ bcnt,
                                             int* __restrict__ tmpE) {
    __shared__ int hist[256];
    __shared__ int lbase[256];    // this block's allocated base within each bucket (bcnt atomic)
    __shared__ int lstart[256];   // exclusive prefix of hist (local slot range start per bucket)
    __shared__ int cur[256];      // local placement cursors
    __shared__ int sc[256];       // scan temp
    __shared__ int staged[4096];  // bucket-sorted packed entries (16 KB)
    __shared__ unsigned char bs[4096];  // bucket id per slot (4 KB)
    const int t = threadIdx.x;
    const int M = E + N;
    const int chunk0 = blockIdx.x * 4096;
    hist[t] = 0;
    __syncthreads();

    int pk[16], bk[16];
#pragma unroll
    for (int j = 0; j < 16; ++j) {
        int i = chunk0 + t + j * 256;
        bk[j] = -1;
        if (i < M) {
            int ss, dd;
            if (i < E) { ss = srcI[i]; dd = dstI[i]; }
            else       { ss = i - E;  dd = ss; }
            if ((unsigned)dd < (unsigned)N && (unsigned)ss < (unsigned)N) {
                bk[j] = dd >> BIN_SHIFT;
                pk[j] = (ss << 9) | (dd & 511);
                atomicAdd(&hist[bk[j]], 1);
            }
        }
    }
    __syncthreads();
    const int h = hist[t];
    lbase[t] = (h > 0) ? atomicAdd(&bcnt[t], h) : 0;
    sc[t] = h;
    __syncthreads();
    for (int off = 1; off < 256; off <<= 1) {
        int v = (t >= off) ? sc[t - off] : 0;
        __syncthreads();
        sc[t] += v;
        __syncthreads();
    }
    lstart[t] = sc[t] - h;
    cur[t]    = sc[t] - h;
    __syncthreads();
#pragma unroll
    for (int j = 0; j < 16; ++j) {
        if (bk[j] >= 0) {
            int r = atomicAdd(&cur[bk[j]], 1);
            staged[r] = pk[j];
            bs[r] = (unsigned char)bk[j];
        }
    }
    const int total = sc[255];
    __syncthreads();
    // coalesced write-out: consecutive slots of one bucket -> consecutive global positions
    for (int s = t; s < total; s += 256) {
        int b = bs[s];
        int posInBucket = lbase[b] + (s - lstart[b]);
        if (posInBucket < BCAP) tmpE[(size_t)b * BCAP + posInBucket] = staged[s];
    }
}

// ---------------- Phase B: per-bucket local CSR build + scatter; colOff = src*256 (byte offset) ----------------
__global__ __launch_bounds__(256) void scatter_csr_k(const int* __restrict__ tmpE,
                                                     const int* __restrict__ bcnt,
                                                     int* __restrict__ rowptr,
                                                     int* __restrict__ colOff,
                                                     int N, int K) {
    __shared__ int pre[256];
    __shared__ int cur[512];
    __shared__ int ss[256];
    const int t = threadIdx.x;
    const int b = blockIdx.x;

    int bc = (t < K) ? min(bcnt[t], BCAP) : 0;
    pre[t] = bc;
    __syncthreads();
    for (int off = 1; off < 256; off <<= 1) {
        int v = (t >= off) ? pre[t - off] : 0;
        __syncthreads();
        pre[t] += v;
        __syncthreads();
    }
    const int base_b = (b == 0) ? 0 : pre[b - 1];
    const int cnt_b  = pre[b] - base_b;
    if (b == K - 1 && t == 0) rowptr[N] = pre[K - 1];

    const int nlo = b << BIN_SHIFT;
    const int nhi = min(nlo + (1 << BIN_SHIFT), N);
    const int nn  = nhi - nlo;
    const int* te = tmpE + (size_t)b * BCAP;

    cur[t] = 0;
    cur[t + 256] = 0;
    __syncthreads();
    for (int i = t; i < cnt_b; i += 256) atomicAdd(&cur[te[i] & 511], 1);
    __syncthreads();

    int v0 = cur[2 * t], v1 = cur[2 * t + 1];
    ss[t] = v0 + v1;
    __syncthreads();
    for (int off = 1; off < 256; off <<= 1) {
        int v = (t >= off) ? ss[t - off] : 0;
        __syncthreads();
        ss[t] += v;
        __syncthreads();
    }
    int e0 = (t == 0) ? 0 : ss[t - 1];
    int e1 = e0 + v0;
    if (2 * t < nn)     rowptr[nlo + 2 * t]     = base_b + e0;
    if (2 * t + 1 < nn) rowptr[nlo + 2 * t + 1] = base_b + e1;
    cur[2 * t] = e0;
    cur[2 * t + 1] = e1;
    __syncthreads();

    for (int i = t; i < cnt_b; i += 256) {
        int v = te[i];
        int r = atomicAdd(&cur[v & 511], 1);
        colOff[base_b + r] = ((unsigned)v >> 9) << 8;   // byte offset of src's 256B Hbuf row
    }
}

// ---------------- h = X @ W via split-bf16 MFMA; bf16 Hout + log2e-scaled fp32 alphas ----------------
// X@W ~= Xh@Wh + Xl@Wh + Xh@Wl (dropped Xl@Wl ~2^-18) -> fp32-grade accuracy.
// B-fragments from the WB contiguous layout: one 1KB coalesced segment per (ks,f) wave-load.
__global__ __launch_bounds__(256) void gemm_mfma_k(const float* __restrict__ X,
                                                   const unsigned short* __restrict__ Wh,
                                                   const unsigned short* __restrict__ Wl,
                                                   const float* __restrict__ a_s,
                                                   const float* __restrict__ a_d,
                                                   unsigned short* __restrict__ Hout,
                                                   float* __restrict__ asrc,
                                                   float* __restrict__ adst,
                                                   int N) {
    __shared__ __align__(16) unsigned short hstage[4][32][132];  // +4 pad: conflict-light
    const int tid = threadIdx.x;
    const int wid = tid >> 6;
    const int l   = tid & 63;
    const int l15 = l & 15;
    const int lh  = l >> 4;
    const int waveRow = blockIdx.x * 128 + wid * 32;
    if (waveRow >= N) return;

    f32x4 acc[2][8];
#pragma unroll
    for (int m = 0; m < 2; ++m)
#pragma unroll
        for (int f = 0; f < 8; ++f)
#pragma unroll
            for (int c = 0; c < 4; ++c) acc[m][f][c] = 0.f;

    const int r0 = waveRow + l15;
    const int r1 = waveRow + 16 + l15;
    const size_t xoff0 = (size_t)min(r0, N - 1) * 128;   // clamp: junk rows never stored
    const size_t xoff1 = (size_t)min(r1, N - 1) * 128;
    const int kb = lh * 8;

#pragma unroll
    for (int ks = 0; ks < 4; ++ks) {
        bf16x8 ah[2], al[2];
#pragma unroll
        for (int m = 0; m < 2; ++m) {
            const float* xp = X + (m ? xoff1 : xoff0) + ks * 32 + kb;
            float4 v0 = *(const float4*)xp;
            float4 v1 = *(const float4*)(xp + 4);
            float xs[8] = {v0.x, v0.y, v0.z, v0.w, v1.x, v1.y, v1.z, v1.w};
#pragma unroll
            for (int j = 0; j < 8; ++j) {
                unsigned short h = bf16r(xs[j]);
                float hf = __uint_as_float((unsigned)h << 16);
                ah[m][j] = (short)h;
                al[m][j] = (short)bf16r(xs[j] - hf);
            }
        }
        const unsigned short* wbh = Wh + ks * 4096 + l * 8;
        const unsigned short* wbl = Wl + ks * 4096 + l * 8;
#pragma unroll
        for (int f = 0; f < 8; ++f) {
            bf16x8 wh = *(const bf16x8*)(wbh + f * 512);
            bf16x8 wl = *(const bf16x8*)(wbl + f * 512);
#pragma unroll
            for (int m = 0; m < 2; ++m) {
                acc[m][f] = __builtin_amdgcn_mfma_f32_16x16x32_bf16(ah[m], wh, acc[m][f], 0, 0, 0);
                acc[m][f] = __builtin_amdgcn_mfma_f32_16x16x32_bf16(al[m], wh, acc[m][f], 0, 0, 0);
                acc[m][f] = __builtin_amdgcn_mfma_f32_16x16x32_bf16(ah[m], wl, acc[m][f], 0, 0, 0);
            }
        }
    }

    float asf[8], adf[8];
#pragma unroll
    for (int f = 0; f < 8; ++f) {
        asf[f] = a_s[f * 16 + l15];
        adf[f] = a_d[f * 16 + l15];
    }
    const int q = l15;
#pragma unroll
    for (int m = 0; m < 2; ++m) {
#pragma unroll
        for (int r = 0; r < 4; ++r) {
            float ps[4] = {0.f, 0.f, 0.f, 0.f};
            float pd[4] = {0.f, 0.f, 0.f, 0.f};
#pragma unroll
            for (int f = 0; f < 8; ++f) {
                float v = acc[m][f][r];
                ps[f >> 1] = fmaf(v, asf[f], ps[f >> 1]);
                pd[f >> 1] = fmaf(v, adf[f], pd[f >> 1]);
                hstage[wid][m * 16 + lh * 4 + r][f * 16 + l15] = bf16r(v);
            }
#pragma unroll
            for (int mask = 1; mask < 16; mask <<= 1) {
#pragma unroll
                for (int h = 0; h < 4; ++h) {
                    ps[h] += __shfl_xor(ps[h], mask);
                    pd[h] += __shfl_xor(pd[h], mask);
                }
            }
            int row = waveRow + m * 16 + lh * 4 + r;
            if (q < 8 && row < N) {
                float v0 = (q & 1) ? ps[1] : ps[0];
                float v1 = (q & 1) ? ps[3] : ps[2];
                float vs = (q & 2) ? v1 : v0;
                float w0 = (q & 1) ? pd[1] : pd[0];
                float w1 = (q & 1) ? pd[3] : pd[2];
                float vd = (q & 2) ? w1 : w0;
                // pre-scale by log2(e): aggregate uses native exp2 (lrelu is pos-homogeneous)
                if (q < 4) asrc[row * 4 + q] = vs * LOG2E;
                else       adst[row * 4 + (q - 4)] = vd * LOG2E;
            }
        }
    }

    // coalesced bf16 store: 16 lanes cover one 256B h-row, 4 rows per iteration
#pragma unroll
    for (int it = 0; it < 8; ++it) {
        int row = it * 4 + lh;
        const unsigned short* hp = &hstage[wid][row][l15 * 8];
        uint2 aa = *(const uint2*)hp;
        uint2 bb = *(const uint2*)(hp + 4);
        int grow = waveRow + row;
        if (grow < N) {
            uint4 o;
            o.x = aa.x; o.y = aa.y; o.z = bb.x; o.w = bb.y;
            *(uint4*)&Hout[(size_t)grow * 128 + l15 * 8] = o;
        }
    }
}

// ---------------- aggregation: one wave per dst node; all-8-wide predicated chunks (no serial tail) ----------------
// w = exp2(lrelu(asrc'+adst')) with alphas pre-scaled by log2e == exp(lrelu(asrc+adst)).
// Invalid lanes in the last chunk read edge e-1 (valid memory) with w forced to exact 0:
// fmaf(0,h,acc)==acc and sw+=0 are bit-exact, so output matches the serial-tail version.
__global__ __launch_bounds__(256) void aggregate_k(const unsigned short* __restrict__ Hbuf,
                                                   const float* __restrict__ asrc,
                                                   const float* __restrict__ adst,
                                                   const int* __restrict__ rowptr,
                                                   const int* __restrict__ colOff,
                                                   const float* __restrict__ bias,
                                                   float* __restrict__ out, int N) {
    int wave = (blockIdx.x * 256 + threadIdx.x) >> 6;
    int lane = threadIdx.x & 63;
    if (wave >= N) return;
    const int n = wave;
    const int c0 = lane * 2;
    const int head = c0 >> 5;
    const float adh = adst[n * 4 + head];
    const char* Hb = (const char*)Hbuf;
    const char* As = (const char*)asrc;
    const int hoff = c0 * 2;            // byte offset of this lane's h dword in a 256B row
    const int aoff = head * 4;

    int b = __builtin_amdgcn_readfirstlane(rowptr[n]);
    int e = __builtin_amdgcn_readfirstlane(rowptr[n + 1]);
    float acc0 = 0.f, acc1 = 0.f, sw = 0.f;
    for (int p = b; p < e; p += 8) {
        int off[8];
#pragma unroll
        for (int j = 0; j < 8; ++j) off[j] = colOff[min(p + j, e - 1)];
        float a[8];
#pragma unroll
        for (int j = 0; j < 8; ++j) a[j] = *(const float*)(As + (off[j] >> 4) + aoff);
        unsigned hu[8];
#pragma unroll
        for (int j = 0; j < 8; ++j) hu[j] = *(const unsigned*)(Hb + off[j] + hoff);
#pragma unroll
        for (int j = 0; j < 8; ++j) {
            float x = a[j] + adh;
            float w = (p + j < e) ? EXP2(fmaxf(x, NEG_SLOPE * x)) : 0.f;
            sw += w;
            acc0 = fmaf(w, bfu_lo(hu[j]), acc0);
            acc1 = fmaf(w, bfu_hi(hu[j]), acc1);
        }
    }
    float inv = 1.f / sw;
    float o0 = fmaxf(acc0 * inv + bias[c0], 0.f);
    float o1 = fmaxf(acc1 * inv + bias[c0 + 1], 0.f);
    *(float2*)&out[(size_t)n * 128 + c0] = make_float2(o0, o1);
}

// ---------------- launch: 7 dispatches ----------------

extern "C" void kernel_launch(void* const* d_in, const int* in_sizes, int n_in,
                              void* d_out, int out_size, void* d_ws, size_t ws_size,
                              hipStream_t stream) {
    const float* X   = (const float*)d_in[0];
    const int*   EI  = (const int*)d_in[1];
    const float* W1  = (const float*)d_in[2];
    const float* as1 = (const float*)d_in[3];
    const float* ad1 = (const float*)d_in[4];
    const float* b1  = (const float*)d_in[5];
    const float* W2  = (const float*)d_in[6];
    const float* as2 = (const float*)d_in[7];
    const float* ad2 = (const float*)d_in[8];
    const float* b2  = (const float*)d_in[9];

    const int N = in_sizes[0] / 128;
    const int E = in_sizes[1] / 2;
    const int M = E + N;
    const int K = (N + (1 << BIN_SHIFT) - 1) >> BIN_SHIFT;   // <= 256 for N <= 131072
    const int* srcI = EI;
    const int* dstI = EI + E;

    char* w = (char*)d_ws;
    auto alloc = [&](size_t bytes) {
        char* p = w;
        w += (bytes + 255) & ~(size_t)255;
        return p;
    };
    unsigned short* Hbuf = (unsigned short*)alloc((size_t)N * 128 * 2);  // bf16, 256B rows
    float* asrc   = (float*)alloc((size_t)N * 4 * 4);
    float* adst   = (float*)alloc((size_t)N * 4 * 4);
    int*   rowptr = (int*)alloc((size_t)(N + 1) * 4);
    int*   colOff = (int*)alloc((size_t)M * 4);
    int*   tmpE   = (int*)alloc((size_t)K * BCAP * 4);       // packed (src<<9 | dst&511)
    int*   bcnt   = (int*)alloc(256 * 4);
    unsigned short* Wt1h = (unsigned short*)alloc(128 * 128 * 2);
    unsigned short* Wt1l = (unsigned short*)alloc(128 * 128 * 2);
    unsigned short* Wt2h = (unsigned short*)alloc(128 * 128 * 2);
    unsigned short* Wt2l = (unsigned short*)alloc(128 * 128 * 2);

    const int gemmBlocks = (N + 127) / 128;
    float* out = (float*)d_out;

    // 1: W pre-split (fragment-contiguous layout) + bcnt zeroing
    wprep_k<<<128, 256, 0, stream>>>(W1, W2, Wt1h, Wt1l, Wt2h, Wt2l, bcnt);
    // 2: bin edges into buckets (LDS counting sort -> coalesced dense writes)
    bin_k<<<(M + 4095) / 4096, 256, 0, stream>>>(srcI, dstI, E, N, K, bcnt, tmpE);
    // 3: per-bucket CSR build + scatter
    scatter_csr_k<<<K, 256, 0, stream>>>(tmpE, bcnt, rowptr, colOff, N, K);
    // 4: gemm layer 1 (activation staged in d_out, fp32)
    gemm_mfma_k<<<gemmBlocks, 256, 0, stream>>>(X, Wt1h, Wt1l, as1, ad1, Hbuf, asrc, adst, N);
    // 5: aggregate layer 1
    aggregate_k<<<((size_t)N * 64 + 255) / 256, 256, 0, stream>>>(Hbuf, asrc, adst, rowptr, colOff, b1, out, N);
    // 6: gemm layer 2
    gemm_mfma_k<<<gemmBlocks, 256, 0, stream>>>(out, Wt2h, Wt2l, as2, ad2, Hbuf, asrc, adst, N);
    // 7: aggregate layer 2
    aggregate_k<<<((size_t)N * 64 + 255) / 256, 256, 0, stream>>>(Hbuf, asrc, adst, rowptr, colOff, b2, out, N);
}